// Round 7
// baseline (938.250 us; speedup 1.0000x reference)
//
#include <hip/hip_runtime.h>
#include <hip/hip_fp16.h>

#define CIN   64
#define COUT  128
#define HW    56
#define LTAPS 576   // CIN * 9

// ---------------------------------------------------------------------------
// Kernel 1: build G[l][a][co] = (half) lut[a][ weight[co][l] ]
// One thread per (l, a, co-octet); writes half8 (16 B coalesced).
// ---------------------------------------------------------------------------
__global__ __launch_bounds__(256) void build_G(const int* __restrict__ weight,
                                               const float* __restrict__ lut,
                                               uint4* __restrict__ G8) {
    int idx = blockIdx.x * 256 + threadIdx.x;   // idx = (l*256 + a)*16 + c8
    int c8 = idx & 15;
    int la = idx >> 4;
    int a  = la & 255;
    int l  = la >> 8;
    int co = c8 * 8;
    const float* lr = lut + a * 256;
    unsigned int p[4];
#pragma unroll
    for (int j = 0; j < 4; ++j) {
        __half h0 = __float2half(lr[weight[(co + 2 * j + 0) * LTAPS + l]]);
        __half h1 = __float2half(lr[weight[(co + 2 * j + 1) * LTAPS + l]]);
        __half2 pp = __halves2half2(h0, h1);
        p[j] = *(unsigned int*)&pp;
    }
    uint4 v; v.x = p[0]; v.y = p[1]; v.z = p[2]; v.w = p[3];
    G8[idx] = v;
}

// ---------------------------------------------------------------------------
// Kernel 2: main conv, SINGLE-GENERATION grid for L2 tap-synchrony.
// 1568 blocks x 128 threads (2 waves); block = 2x8 pixel tile, all 128 co.
//   q = tid & 15  -> co = 8q..8q+7 (16 B uint4 slice of the 256 B row)
//   s = tid >> 4  -> column s of the tile; pixels (0,s) and (1,s)
// All blocks resident simultaneously (launch_bounds(128,4) keeps VGPR<=128
// -> 16 waves/CU -> 2048-block capacity) and traverse taps l=0..575 in the
// same order, so the 64 KB/tap hot slice of G stays L2-resident: each XCD
// streams G ~once (FETCH ~350 MB vs 830+ MB with multi-generation grids).
// Ping-pong prefetch over 3-tap groups (12 uint4 named regs), fp16 packed
// accumulation flushed to fp32 every 8 ci (72 taps, validated absmax 0.5).
// NOTE: pasted-token member access must be parenthesized -- (p##1).z --
// because 1.z lexes as a single pp-number before ## pasting (round-6 bug).
// ---------------------------------------------------------------------------

#define DECL6(p) uint4 p##0, p##1, p##2, p##3, p##4, p##5;

#define H2C(x) __builtin_bit_cast(__half2, x)

// prefetch group (ci, ky): 3 taps x 2 pixels = 6 rows
#define PF(p, ci, ky)                                                          \
    {                                                                          \
        const unsigned char* sc = sA + (ci) * 40 + (ky) * 10;                  \
        const char* Gl = Gbase + ((size_t)((ci) * 9 + (ky) * 3) << 16);        \
        p##0 = *(const uint4*)(Gl + (0 << 16) + ((int)sc[pxa + 0] << 8));      \
        p##1 = *(const uint4*)(Gl + (1 << 16) + ((int)sc[pxa + 1] << 8));      \
        p##2 = *(const uint4*)(Gl + (2 << 16) + ((int)sc[pxa + 2] << 8));      \
        p##3 = *(const uint4*)(Gl + (0 << 16) + ((int)sc[pxb + 0] << 8));      \
        p##4 = *(const uint4*)(Gl + (1 << 16) + ((int)sc[pxb + 1] << 8));      \
        p##5 = *(const uint4*)(Gl + (2 << 16) + ((int)sc[pxb + 2] << 8));      \
    }

#define CS1A(d)                                                                \
    Aa0 += H2C((d).x); Aa1 += H2C((d).y); Aa2 += H2C((d).z); Aa3 += H2C((d).w);
#define CS1B(d)                                                                \
    Ab0 += H2C((d).x); Ab1 += H2C((d).y); Ab2 += H2C((d).z); Ab3 += H2C((d).w);

#define CS(p)                                                                  \
    CS1A(p##0) CS1A(p##1) CS1A(p##2)                                           \
    CS1B(p##3) CS1B(p##4) CS1B(p##5)

#define FLUSH                                                                  \
    {                                                                          \
        float2 f_;                                                             \
        f_ = __half22float2(Aa0); accA[0] += f_.x; accA[1] += f_.y;            \
        f_ = __half22float2(Aa1); accA[2] += f_.x; accA[3] += f_.y;            \
        f_ = __half22float2(Aa2); accA[4] += f_.x; accA[5] += f_.y;            \
        f_ = __half22float2(Aa3); accA[6] += f_.x; accA[7] += f_.y;            \
        f_ = __half22float2(Ab0); accB[0] += f_.x; accB[1] += f_.y;            \
        f_ = __half22float2(Ab1); accB[2] += f_.x; accB[3] += f_.y;            \
        f_ = __half22float2(Ab2); accB[4] += f_.x; accB[5] += f_.y;            \
        f_ = __half22float2(Ab3); accB[6] += f_.x; accB[7] += f_.y;            \
        Aa0 = z; Aa1 = z; Aa2 = z; Aa3 = z;                                    \
        Ab0 = z; Ab1 = z; Ab2 = z; Ab3 = z;                                    \
    }

__global__ __launch_bounds__(128, 4) void conv_lut(const int* __restrict__ input,
                                                   const __half* __restrict__ G,
                                                   const float* __restrict__ bias,
                                                   float* __restrict__ out) {
    __shared__ unsigned char sA[CIN * 40];   // [ci][4][10] halo of 2x8 tile

    int bx = blockIdx.x;
    int b  = bx / 196;          // 196 = 28*7 tiles per image (2 rows x 8 cols)
    int r  = bx % 196;
    int y0 = (r / 7) * 2;
    int x0 = (r % 7) * 8;

    int tid = threadIdx.x;

    // ---- stage 4x10 patch codes per ci (zero-pad = code 0) ----
    for (int i = tid; i < CIN * 40; i += 128) {
        int ci = i / 40, rr = i % 40;
        int yy = y0 + rr / 10 - 1;
        int xx = x0 + rr % 10 - 1;
        int v = 0;
        if (yy >= 0 && yy < HW && xx >= 0 && xx < HW)
            v = input[((b * CIN + ci) * HW + yy) * HW + xx];
        sA[i] = (unsigned char)v;
    }
    __syncthreads();

    const int q  = tid & 15;            // co octet
    const int s  = tid >> 4;            // tile column 0..7
    const int pxa = s;                  // pixel (0,s)
    const int pxb = 10 + s;             // pixel (1,s)
    const char* Gbase = (const char*)G + q * 16;

    float accA[8] = {0.f, 0.f, 0.f, 0.f, 0.f, 0.f, 0.f, 0.f};
    float accB[8] = {0.f, 0.f, 0.f, 0.f, 0.f, 0.f, 0.f, 0.f};
    const __half2 z = __float2half2_rn(0.f);
    __half2 Aa0 = z, Aa1 = z, Aa2 = z, Aa3 = z;
    __half2 Ab0 = z, Ab1 = z, Ab2 = z, Ab3 = z;

    DECL6(u)
    DECL6(v)
    PF(u, 0, 0);

    for (int ci0 = 0; ci0 < CIN; ci0 += 2) {
        PF(v, ci0, 1);       CS(u)
        PF(u, ci0, 2);       CS(v)
        PF(v, ci0 + 1, 0);   CS(u)
        PF(u, ci0 + 1, 1);   CS(v)
        PF(v, ci0 + 1, 2);   CS(u)
        if (ci0 + 2 < CIN) { PF(u, ci0 + 2, 0); }
        CS(v)
        if (((ci0 + 2) & 7) == 0) { FLUSH }
    }

    // ---- epilogue: bias + store (2 pixels x 8 co) ----
    const int ow  = x0 + s;
    const int cob = q * 8;
#pragma unroll
    for (int j = 0; j < 8; ++j) {
        const int co = cob + j;
        const float bb = bias[co];
        size_t base = ((size_t)(b * COUT + co) * HW + y0) * HW + ow;
        out[base]      = accA[j] + bb;
        out[base + HW] = accB[j] + bb;
    }
}

// ---------------------------------------------------------------------------
// Fallback (ws too small): gather lut directly, fp32 exact. 4x4 tiles.
// ---------------------------------------------------------------------------
__global__ __launch_bounds__(256) void conv_direct(const int* __restrict__ input,
                                                   const int* __restrict__ weight,
                                                   const float* __restrict__ lut,
                                                   const float* __restrict__ bias,
                                                   float* __restrict__ out) {
    __shared__ unsigned char sA[CIN * 36];

    int bx = blockIdx.x;
    int b  = bx / 196;
    int r  = bx % 196;
    int y0 = (r / 14) * 4;
    int x0 = (r % 14) * 4;

    int tid = threadIdx.x;
    for (int i = tid; i < CIN * 36; i += 256) {
        int ci = i / 36, rr = i % 36;
        int yy = y0 + rr / 6 - 1;
        int xx = x0 + rr % 6 - 1;
        int v = 0;
        if (yy >= 0 && yy < HW && xx >= 0 && xx < HW)
            v = input[((b * CIN + ci) * HW + yy) * HW + xx];
        sA[i] = (unsigned char)v;
    }
    __syncthreads();

    const int q  = tid & 31;
    const int g  = tid >> 5;
    const int qv = q * 4;
    const int p0 = g * 2, p1 = p0 + 1;
    const int py0 = p0 >> 2, px0 = p0 & 3;
    const int py1 = p1 >> 2, px1 = p1 & 3;
    const int pb0 = py0 * 6 + px0;
    const int pb1 = py1 * 6 + px1;

    float acc0[4] = {0.f, 0.f, 0.f, 0.f};
    float acc1[4] = {0.f, 0.f, 0.f, 0.f};
    const int off[9] = {0, 1, 2, 6, 7, 8, 12, 13, 14};

    for (int ci = 0; ci < CIN; ++ci) {
        const int cbase = ci * 36;
#pragma unroll
        for (int t = 0; t < 9; ++t) {
            const int l = ci * 9 + t;
            const int a0 = sA[cbase + pb0 + off[t]];
            const int a1 = sA[cbase + pb1 + off[t]];
#pragma unroll
            for (int j = 0; j < 4; ++j) {
                const int w = weight[(qv + j) * LTAPS + l];
                acc0[j] += lut[a0 * 256 + w];
                acc1[j] += lut[a1 * 256 + w];
            }
        }
    }

    const int oh0 = y0 + py0, ow0 = x0 + px0;
    const int oh1 = y0 + py1, ow1 = x0 + px1;
#pragma unroll
    for (int j = 0; j < 4; ++j) {
        const int co = qv + j;
        const float bb = bias[co];
        out[((size_t)(b * COUT + co) * HW + oh0) * HW + ow0] = acc0[j] + bb;
        out[((size_t)(b * COUT + co) * HW + oh1) * HW + ow1] = acc1[j] + bb;
    }
}

// ---------------------------------------------------------------------------
extern "C" void kernel_launch(void* const* d_in, const int* in_sizes, int n_in,
                              void* d_out, int out_size, void* d_ws, size_t ws_size,
                              hipStream_t stream) {
    const int*   input  = (const int*)d_in[0];
    const int*   weight = (const int*)d_in[1];
    const float* lut    = (const float*)d_in[2];
    const float* bias   = (const float*)d_in[3];
    float*       out    = (float*)d_out;

    const size_t g_bytes = (size_t)LTAPS * 256 * 128 * sizeof(__half);  // ~37.7 MB

    if (ws_size >= g_bytes) {
        build_G<<<LTAPS * 16, 256, 0, stream>>>(weight, lut, (uint4*)d_ws);
        conv_lut<<<8 * 196, 128, 0, stream>>>(input, (const __half*)d_ws, bias, out);
    } else {
        conv_direct<<<8 * 196, 256, 0, stream>>>(input, weight, lut, bias, out);
    }
}

// Round 8
// 269.056 us; speedup vs baseline: 3.4872x; 3.4872x over previous
//
#include <hip/hip_runtime.h>

#define CIN   64
#define COUT  128
#define HW    56
#define LTAPS 576   // CIN * 9

// ws layout: float scale at ws[0]; u8 G table at ws + 256 bytes.
// G[l][a][co] u8, offset ((l*256 + a) << 7) + co   (row = 128 B)

// ---------------------------------------------------------------------------
// Kernel 0: s = max|lut| / 127  (single block; lut is 256x256 = 16384 float4)
// ---------------------------------------------------------------------------
__global__ __launch_bounds__(256) void lut_absmax(const float* __restrict__ lut,
                                                  float* __restrict__ ws_scale) {
    __shared__ float red[4];
    int tid = threadIdx.x;
    float m = 0.f;
    const float4* l4 = (const float4*)lut;
    for (int i = tid; i < 16384; i += 256) {
        float4 v = l4[i];
        m = fmaxf(m, fmaxf(fmaxf(fabsf(v.x), fabsf(v.y)),
                           fmaxf(fabsf(v.z), fabsf(v.w))));
    }
    for (int off = 32; off > 0; off >>= 1)
        m = fmaxf(m, __shfl_down(m, off, 64));
    if ((tid & 63) == 0) red[tid >> 6] = m;
    __syncthreads();
    if (tid == 0) {
        m = fmaxf(fmaxf(red[0], red[1]), fmaxf(red[2], red[3]));
        ws_scale[0] = m / 127.0f;
    }
}

// ---------------------------------------------------------------------------
// Kernel 1: build u8 G: q = rint(lut[a, w[co,l]] / s) + 128   (biased u8)
// One thread per (l, a, co-octet); writes 8 B coalesced.
// ---------------------------------------------------------------------------
__global__ __launch_bounds__(256) void build_G8(const int* __restrict__ weight,
                                                const float* __restrict__ lut,
                                                const float* __restrict__ ws_scale,
                                                uint2* __restrict__ G) {
    int idx = blockIdx.x * 256 + threadIdx.x;   // (l*256 + a)*16 + c8
    int c8 = idx & 15;
    int la = idx >> 4;
    int a  = la & 255;
    int l  = la >> 8;
    int co = c8 * 8;
    float inv = 1.0f / ws_scale[0];
    const float* lr = lut + a * 256;
    unsigned int w0 = 0, w1 = 0;
#pragma unroll
    for (int j = 0; j < 8; ++j) {
        float x = lr[weight[(co + j) * LTAPS + l]];
        int qv = (int)rintf(x * inv) + 128;
        qv = qv < 0 ? 0 : (qv > 255 ? 255 : qv);
        if (j < 4) w0 |= (unsigned int)qv << (8 * j);
        else       w1 |= (unsigned int)qv << (8 * (j - 4));
    }
    uint2 v; v.x = w0; v.y = w1;
    G[idx] = v;
}

// ---------------------------------------------------------------------------
// Kernel 2: main conv, u8 rows (128 B -> half the 64-B L2 lines of fp16).
// 784 blocks x 256 threads (all resident -> single generation, tap-synced).
// Block = 4x8 pixel tile of one image, all 128 co.
//   q = tid & 7  -> co = 16q..16q+15 (one 16 B uint4 = 16 u8 codes)
//   g = tid >> 3 -> pixel g of the 32-pixel tile
// Accumulate: per dword d (4 co): aL += d & 0x00FF00FF (co 0,2 as u16 fields),
// aH += (d>>8) & 0x00FF00FF (co 1,3). Plain u32 adds -- fields can't carry
// (max 16 ci * 9 * 255 = 36720 < 65536). Flush to u32 every 16 ci.
// Epilogue: out = s * (acc - 576*128) + bias   (u8 bias removal exact).
// ---------------------------------------------------------------------------
__global__ __launch_bounds__(256) void conv_i8(const int* __restrict__ input,
                                               const unsigned char* __restrict__ G,
                                               const float* __restrict__ bias,
                                               const float* __restrict__ ws_scale,
                                               float* __restrict__ out) {
    __shared__ unsigned char sA[CIN * 60];   // [ci][6][10] halo of 4x8 tile

    int bx = blockIdx.x;
    int b  = bx / 98;           // 98 = 14*7 tiles per image (4 rows x 8 cols)
    int r  = bx % 98;
    int y0 = (r / 7) * 4;
    int x0 = (r % 7) * 8;

    int tid = threadIdx.x;

    // ---- stage 6x10 patch codes per ci (zero-pad = code 0) ----
    for (int i = tid; i < CIN * 60; i += 256) {
        int ci = i / 60, rr = i % 60;
        int yy = y0 + rr / 10 - 1;
        int xx = x0 + rr % 10 - 1;
        int v = 0;
        if (yy >= 0 && yy < HW && xx >= 0 && xx < HW)
            v = input[((b * CIN + ci) * HW + yy) * HW + xx];
        sA[i] = (unsigned char)v;
    }
    __syncthreads();

    const int q  = tid & 7;             // co 16-group
    const int g  = tid >> 3;            // pixel 0..31
    const int py = g >> 3, px = g & 7;
    const int pb = py * 10 + px;
    const unsigned char* Gq = G + q * 16;

    unsigned int acc0  = 0, acc1  = 0, acc2  = 0, acc3  = 0;
    unsigned int acc4  = 0, acc5  = 0, acc6  = 0, acc7  = 0;
    unsigned int acc8  = 0, acc9  = 0, acc10 = 0, acc11 = 0;
    unsigned int acc12 = 0, acc13 = 0, acc14 = 0, acc15 = 0;

    for (int ci0 = 0; ci0 < CIN; ci0 += 16) {
        unsigned int aL0 = 0, aL1 = 0, aL2 = 0, aL3 = 0;
        unsigned int aH0 = 0, aH1 = 0, aH2 = 0, aH3 = 0;
        for (int ci = ci0; ci < ci0 + 16; ++ci) {
            const unsigned char* sc = sA + ci * 60 + pb;
            const unsigned char* Gl = Gq + ((size_t)(ci * 9) << 15);
#pragma unroll
            for (int t = 0; t < 9; ++t) {
                const int code = sc[(t / 3) * 10 + (t % 3)];
                uint4 d = *(const uint4*)(Gl + ((size_t)t << 15) + (code << 7));
                aL0 += d.x & 0x00FF00FFu;  aH0 += (d.x >> 8) & 0x00FF00FFu;
                aL1 += d.y & 0x00FF00FFu;  aH1 += (d.y >> 8) & 0x00FF00FFu;
                aL2 += d.z & 0x00FF00FFu;  aH2 += (d.z >> 8) & 0x00FF00FFu;
                aL3 += d.w & 0x00FF00FFu;  aH3 += (d.w >> 8) & 0x00FF00FFu;
            }
        }
        acc0  += aL0 & 0xFFFFu;  acc2  += aL0 >> 16;
        acc1  += aH0 & 0xFFFFu;  acc3  += aH0 >> 16;
        acc4  += aL1 & 0xFFFFu;  acc6  += aL1 >> 16;
        acc5  += aH1 & 0xFFFFu;  acc7  += aH1 >> 16;
        acc8  += aL2 & 0xFFFFu;  acc10 += aL2 >> 16;
        acc9  += aH2 & 0xFFFFu;  acc11 += aH2 >> 16;
        acc12 += aL3 & 0xFFFFu;  acc14 += aL3 >> 16;
        acc13 += aH3 & 0xFFFFu;  acc15 += aH3 >> 16;
    }

    // ---- epilogue: remove u8 bias, scale, add conv bias, store ----
    const float s  = ws_scale[0];
    const int   oh = y0 + py, ow = x0 + px;
    const int   cob = q * 16;
    unsigned int accs[16] = {acc0, acc1, acc2,  acc3,  acc4,  acc5,  acc6,  acc7,
                             acc8, acc9, acc10, acc11, acc12, acc13, acc14, acc15};
#pragma unroll
    for (int j = 0; j < 16; ++j) {
        const int co = cob + j;
        out[((size_t)(b * COUT + co) * HW + oh) * HW + ow] =
            s * (float)((int)accs[j] - 73728) + bias[co];   // 73728 = 576*128
    }
}

// ---------------------------------------------------------------------------
// Fallback (ws too small): gather lut directly, fp32 exact. 4x4 tiles.
// ---------------------------------------------------------------------------
__global__ __launch_bounds__(256) void conv_direct(const int* __restrict__ input,
                                                   const int* __restrict__ weight,
                                                   const float* __restrict__ lut,
                                                   const float* __restrict__ bias,
                                                   float* __restrict__ out) {
    __shared__ unsigned char sA[CIN * 36];

    int bx = blockIdx.x;
    int b  = bx / 196;
    int r  = bx % 196;
    int y0 = (r / 14) * 4;
    int x0 = (r % 14) * 4;

    int tid = threadIdx.x;
    for (int i = tid; i < CIN * 36; i += 256) {
        int ci = i / 36, rr = i % 36;
        int yy = y0 + rr / 6 - 1;
        int xx = x0 + rr % 6 - 1;
        int v = 0;
        if (yy >= 0 && yy < HW && xx >= 0 && xx < HW)
            v = input[((b * CIN + ci) * HW + yy) * HW + xx];
        sA[i] = (unsigned char)v;
    }
    __syncthreads();

    const int q  = tid & 31;
    const int g  = tid >> 5;
    const int qv = q * 4;
    const int p0 = g * 2, p1 = p0 + 1;
    const int py0 = p0 >> 2, px0 = p0 & 3;
    const int py1 = p1 >> 2, px1 = p1 & 3;
    const int pb0 = py0 * 6 + px0;
    const int pb1 = py1 * 6 + px1;

    float acc0[4] = {0.f, 0.f, 0.f, 0.f};
    float acc1[4] = {0.f, 0.f, 0.f, 0.f};
    const int off[9] = {0, 1, 2, 6, 7, 8, 12, 13, 14};

    for (int ci = 0; ci < CIN; ++ci) {
        const int cbase = ci * 36;
#pragma unroll
        for (int t = 0; t < 9; ++t) {
            const int l = ci * 9 + t;
            const int a0 = sA[cbase + pb0 + off[t]];
            const int a1 = sA[cbase + pb1 + off[t]];
#pragma unroll
            for (int j = 0; j < 4; ++j) {
                const int w = weight[(qv + j) * LTAPS + l];
                acc0[j] += lut[a0 * 256 + w];
                acc1[j] += lut[a1 * 256 + w];
            }
        }
    }

    const int oh0 = y0 + py0, ow0 = x0 + px0;
    const int oh1 = y0 + py1, ow1 = x0 + px1;
#pragma unroll
    for (int j = 0; j < 4; ++j) {
        const int co = qv + j;
        const float bb = bias[co];
        out[((size_t)(b * COUT + co) * HW + oh0) * HW + ow0] = acc0[j] + bb;
        out[((size_t)(b * COUT + co) * HW + oh1) * HW + ow1] = acc1[j] + bb;
    }
}

// ---------------------------------------------------------------------------
extern "C" void kernel_launch(void* const* d_in, const int* in_sizes, int n_in,
                              void* d_out, int out_size, void* d_ws, size_t ws_size,
                              hipStream_t stream) {
    const int*   input  = (const int*)d_in[0];
    const int*   weight = (const int*)d_in[1];
    const float* lut    = (const float*)d_in[2];
    const float* bias   = (const float*)d_in[3];
    float*       out    = (float*)d_out;

    const size_t g_bytes = 256 + (size_t)LTAPS * 256 * 128;   // ~18.9 MB

    if (ws_size >= g_bytes) {
        float*         ws_scale = (float*)d_ws;
        unsigned char* G        = (unsigned char*)d_ws + 256;
        lut_absmax<<<1, 256, 0, stream>>>(lut, ws_scale);
        build_G8<<<LTAPS * 16, 256, 0, stream>>>(weight, lut, ws_scale, (uint2*)G);
        conv_i8<<<8 * 98, 256, 0, stream>>>(input, G, bias, ws_scale, out);
    } else {
        conv_direct<<<8 * 196, 256, 0, stream>>>(input, weight, lut, bias, out);
    }
}

// Round 9
// 210.171 us; speedup vs baseline: 4.4642x; 1.2802x over previous
//
#include <hip/hip_runtime.h>

#define CIN   64
#define COUT  128
#define HW    56
#define LTAPS 576   // CIN * 9

// ws layout: float scale at ws[0]; u8 G table at ws + 256 bytes.
// G[l][a][co] u8, offset ((l*256 + a) << 7) + co   (row = 128 B, tap slab 32 KB)

// ---------------------------------------------------------------------------
// Kernel 0: s = max|lut| / 127
// ---------------------------------------------------------------------------
__global__ __launch_bounds__(256) void lut_absmax(const float* __restrict__ lut,
                                                  float* __restrict__ ws_scale) {
    __shared__ float red[4];
    int tid = threadIdx.x;
    float m = 0.f;
    const float4* l4 = (const float4*)lut;
    for (int i = tid; i < 16384; i += 256) {
        float4 v = l4[i];
        m = fmaxf(m, fmaxf(fmaxf(fabsf(v.x), fabsf(v.y)),
                           fmaxf(fabsf(v.z), fabsf(v.w))));
    }
    for (int off = 32; off > 0; off >>= 1)
        m = fmaxf(m, __shfl_down(m, off, 64));
    if ((tid & 63) == 0) red[tid >> 6] = m;
    __syncthreads();
    if (tid == 0) {
        m = fmaxf(fmaxf(red[0], red[1]), fmaxf(red[2], red[3]));
        ws_scale[0] = m / 127.0f;
    }
}

// ---------------------------------------------------------------------------
// Kernel 1: build u8 G: q = rint(lut[a, w[co,l]] / s) + 128   (biased u8)
// ---------------------------------------------------------------------------
__global__ __launch_bounds__(256) void build_G8(const int* __restrict__ weight,
                                                const float* __restrict__ lut,
                                                const float* __restrict__ ws_scale,
                                                uint2* __restrict__ G) {
    int idx = blockIdx.x * 256 + threadIdx.x;   // (l*256 + a)*16 + c8
    int c8 = idx & 15;
    int la = idx >> 4;
    int a  = la & 255;
    int l  = la >> 8;
    int co = c8 * 8;
    float inv = 1.0f / ws_scale[0];
    const float* lr = lut + a * 256;
    unsigned int w0 = 0, w1 = 0;
#pragma unroll
    for (int j = 0; j < 8; ++j) {
        float x = lr[weight[(co + j) * LTAPS + l]];
        int qv = (int)rintf(x * inv) + 128;
        qv = qv < 0 ? 0 : (qv > 255 ? 255 : qv);
        if (j < 4) w0 |= (unsigned int)qv << (8 * j);
        else       w1 |= (unsigned int)qv << (8 * (j - 4));
    }
    uint2 v; v.x = w0; v.y = w1;
    G[idx] = v;
}

// ---------------------------------------------------------------------------
// Kernel 2: main conv, u8 rows, 2x concurrency vs round 8.
// 1568 blocks x 256 threads (24.5 waves/CU, all resident -> single generation).
// Block = 2x8 pixel tile of one image, all 128 co.
//   q = tid & 15 -> co = 8q..8q+7 (one 8 B uint2 of the 128 B row)
//   g = tid >> 4 -> pixel g of the 16-pixel tile
// Depth-6 ping-pong prefetch in named uint2 regs (12 VGPR); per-byte
// accumulation via v_dot4_u32_u8 with byte-selector (1 VALU/co/tap, exact
// u32 sums, no flush). Total VGPR target <= 64 to keep 8 waves/SIMD capacity.
// Epilogue: out = s * (acc - 576*128) + bias.
// ---------------------------------------------------------------------------

#if __has_builtin(__builtin_amdgcn_udot4)
#define ACCB(d, sh, acc) acc = __builtin_amdgcn_udot4((d), 1u << (8 * (sh)), (acc), false);
#else
#define ACCB(d, sh, acc) acc += ((d) >> (8 * (sh))) & 0xFFu;
#endif

#define DECL3(p) uint2 p##0, p##1, p##2;

#define PF3(p, ci, ky)                                                         \
    {                                                                          \
        const unsigned char* sc = sA + (ci) * 40 + pb + (ky) * 10;             \
        const unsigned char* Gl = Gq + ((size_t)((ci) * 9 + (ky) * 3) << 15);  \
        p##0 = *(const uint2*)(Gl + (0 << 15) + ((int)sc[0] << 7));            \
        p##1 = *(const uint2*)(Gl + (1 << 15) + ((int)sc[1] << 7));            \
        p##2 = *(const uint2*)(Gl + (2 << 15) + ((int)sc[2] << 7));            \
    }

#define ACC8(d)                                                                \
    ACCB((d).x, 0, a0) ACCB((d).x, 1, a1) ACCB((d).x, 2, a2) ACCB((d).x, 3, a3)\
    ACCB((d).y, 0, a4) ACCB((d).y, 1, a5) ACCB((d).y, 2, a6) ACCB((d).y, 3, a7)

#define CS3(p) ACC8(p##0) ACC8(p##1) ACC8(p##2)

__global__ __launch_bounds__(256) void conv_i8(const int* __restrict__ input,
                                               const unsigned char* __restrict__ G,
                                               const float* __restrict__ bias,
                                               const float* __restrict__ ws_scale,
                                               float* __restrict__ out) {
    __shared__ unsigned char sA[CIN * 40];   // [ci][4][10] halo of 2x8 tile

    int bx = blockIdx.x;
    int b  = bx / 196;          // 196 = 28*7 tiles per image (2 rows x 8 cols)
    int r  = bx % 196;
    int y0 = (r / 7) * 2;
    int x0 = (r % 7) * 8;

    int tid = threadIdx.x;

    // ---- stage 4x10 patch codes per ci (zero-pad = code 0) ----
    for (int i = tid; i < CIN * 40; i += 256) {
        int ci = i / 40, rr = i % 40;
        int yy = y0 + rr / 10 - 1;
        int xx = x0 + rr % 10 - 1;
        int v = 0;
        if (yy >= 0 && yy < HW && xx >= 0 && xx < HW)
            v = input[((b * CIN + ci) * HW + yy) * HW + xx];
        sA[i] = (unsigned char)v;
    }
    __syncthreads();

    const int q  = tid & 15;            // co octet
    const int g  = tid >> 4;            // pixel 0..15
    const int py = g >> 3, px = g & 7;  // 2 rows x 8 cols
    const int pb = py * 10 + px;
    const unsigned char* Gq = G + q * 8;

    unsigned int a0 = 0, a1 = 0, a2 = 0, a3 = 0;
    unsigned int a4 = 0, a5 = 0, a6 = 0, a7 = 0;

    DECL3(u)
    DECL3(v)
    PF3(u, 0, 0);

    for (int ci0 = 0; ci0 < CIN; ci0 += 2) {
        PF3(v, ci0, 1);       CS3(u)
        PF3(u, ci0, 2);       CS3(v)
        PF3(v, ci0 + 1, 0);   CS3(u)
        PF3(u, ci0 + 1, 1);   CS3(v)
        PF3(v, ci0 + 1, 2);   CS3(u)
        if (ci0 + 2 < CIN) { PF3(u, ci0 + 2, 0); }
        CS3(v)
    }

    // ---- epilogue: remove u8 bias, scale, add conv bias, store ----
    const float s  = ws_scale[0];
    const int   oh = y0 + py, ow = x0 + px;
    const int   cob = q * 8;
    const size_t pixoff = (size_t)oh * HW + ow;
    float* ob = out + (size_t)(b * COUT + cob) * (HW * HW) + pixoff;
    const float* bb = bias + cob;
    ob[0 * HW * HW] = s * (float)((int)a0 - 73728) + bb[0];
    ob[1 * HW * HW] = s * (float)((int)a1 - 73728) + bb[1];
    ob[2 * HW * HW] = s * (float)((int)a2 - 73728) + bb[2];
    ob[3 * HW * HW] = s * (float)((int)a3 - 73728) + bb[3];
    ob[4 * HW * HW] = s * (float)((int)a4 - 73728) + bb[4];
    ob[5 * HW * HW] = s * (float)((int)a5 - 73728) + bb[5];
    ob[6 * HW * HW] = s * (float)((int)a6 - 73728) + bb[6];
    ob[7 * HW * HW] = s * (float)((int)a7 - 73728) + bb[7];
}

// ---------------------------------------------------------------------------
// Fallback (ws too small): gather lut directly, fp32 exact. 4x4 tiles.
// ---------------------------------------------------------------------------
__global__ __launch_bounds__(256) void conv_direct(const int* __restrict__ input,
                                                   const int* __restrict__ weight,
                                                   const float* __restrict__ lut,
                                                   const float* __restrict__ bias,
                                                   float* __restrict__ out) {
    __shared__ unsigned char sA[CIN * 36];

    int bx = blockIdx.x;
    int b  = bx / 196;
    int r  = bx % 196;
    int y0 = (r / 14) * 4;
    int x0 = (r % 14) * 4;

    int tid = threadIdx.x;
    for (int i = tid; i < CIN * 36; i += 256) {
        int ci = i / 36, rr = i % 36;
        int yy = y0 + rr / 6 - 1;
        int xx = x0 + rr % 6 - 1;
        int v = 0;
        if (yy >= 0 && yy < HW && xx >= 0 && xx < HW)
            v = input[((b * CIN + ci) * HW + yy) * HW + xx];
        sA[i] = (unsigned char)v;
    }
    __syncthreads();

    const int q  = tid & 31;
    const int g  = tid >> 5;
    const int qv = q * 4;
    const int p0 = g * 2, p1 = p0 + 1;
    const int py0 = p0 >> 2, px0 = p0 & 3;
    const int py1 = p1 >> 2, px1 = p1 & 3;
    const int pb0 = py0 * 6 + px0;
    const int pb1 = py1 * 6 + px1;

    float acc0[4] = {0.f, 0.f, 0.f, 0.f};
    float acc1[4] = {0.f, 0.f, 0.f, 0.f};
    const int off[9] = {0, 1, 2, 6, 7, 8, 12, 13, 14};

    for (int ci = 0; ci < CIN; ++ci) {
        const int cbase = ci * 36;
#pragma unroll
        for (int t = 0; t < 9; ++t) {
            const int l = ci * 9 + t;
            const int a0 = sA[cbase + pb0 + off[t]];
            const int a1 = sA[cbase + pb1 + off[t]];
#pragma unroll
            for (int j = 0; j < 4; ++j) {
                const int w = weight[(qv + j) * LTAPS + l];
                acc0[j] += lut[a0 * 256 + w];
                acc1[j] += lut[a1 * 256 + w];
            }
        }
    }

    const int oh0 = y0 + py0, ow0 = x0 + px0;
    const int oh1 = y0 + py1, ow1 = x0 + px1;
#pragma unroll
    for (int j = 0; j < 4; ++j) {
        const int co = qv + j;
        const float bb = bias[co];
        out[((size_t)(b * COUT + co) * HW + oh0) * HW + ow0] = acc0[j] + bb;
        out[((size_t)(b * COUT + co) * HW + oh1) * HW + ow1] = acc1[j] + bb;
    }
}

// ---------------------------------------------------------------------------
extern "C" void kernel_launch(void* const* d_in, const int* in_sizes, int n_in,
                              void* d_out, int out_size, void* d_ws, size_t ws_size,
                              hipStream_t stream) {
    const int*   input  = (const int*)d_in[0];
    const int*   weight = (const int*)d_in[1];
    const float* lut    = (const float*)d_in[2];
    const float* bias   = (const float*)d_in[3];
    float*       out    = (float*)d_out;

    const size_t g_bytes = 256 + (size_t)LTAPS * 256 * 128;   // ~18.9 MB

    if (ws_size >= g_bytes) {
        float*         ws_scale = (float*)d_ws;
        unsigned char* G        = (unsigned char*)d_ws + 256;
        lut_absmax<<<1, 256, 0, stream>>>(lut, ws_scale);
        build_G8<<<LTAPS * 16, 256, 0, stream>>>(weight, lut, ws_scale, (uint2*)G);
        conv_i8<<<8 * 196, 256, 0, stream>>>(input, G, bias, ws_scale, out);
    } else {
        conv_direct<<<8 * 196, 256, 0, stream>>>(input, weight, lut, bias, out);
    }
}